// Round 5
// baseline (644.262 us; speedup 1.0000x reference)
//
#include <hip/hip_runtime.h>

typedef __attribute__((ext_vector_type(8))) short short8;
typedef __attribute__((ext_vector_type(4))) float floatx4;
typedef unsigned short ushort_t;
typedef unsigned int u32;

// ---------- helpers ----------
__device__ __forceinline__ ushort_t f2bf(float x) {
  union { float f; unsigned int u; } v; v.f = x;
  unsigned int u = v.u;
  return (ushort_t)((u + 0x7FFFu + ((u >> 16) & 1u)) >> 16);  // RNE
}
__device__ __forceinline__ unsigned int pk2(float a, float b) {
  return (unsigned int)f2bf(a) | ((unsigned int)f2bf(b) << 16);
}
// async global->LDS, 16B per lane (dest = wave-uniform base + lane*16)
__device__ __forceinline__ void gl_lds16(const void* g, void* l) {
  __builtin_amdgcn_global_load_lds(
      (const __attribute__((address_space(1))) u32*)g,
      (__attribute__((address_space(3))) u32*)l, 16, 0, 0);
}

// Tiled layout, RB in {128,256}:  T[rb][kc][r][j],  element (row,k) at
//   ((row/RB)*(K/8) + k/8)*RB*8 + (row%RB)*8 + (k%8)
// One block's K-tile (32 k, RB rows) is RB*64 bytes CONTIGUOUS and identical
// to the LDS quad-major layout -> straight global_load_lds copy.

// ---------- prep: weights -> tiled bf16 (RB=128) ----------
__global__ void prep_t(const float* __restrict__ W1, const float* __restrict__ W2,
                       ushort_t* __restrict__ W1T, ushort_t* __restrict__ W2T) {
  int idx = blockIdx.x * 256 + threadIdx.x;   // 0 .. 131071
  int m = idx >> 9, k = idx & 511;            // W1: m in 256, k in 512
  W1T[((m >> 7) * 64 + (k >> 3)) * 1024 + (m & 127) * 8 + (k & 7)] = f2bf(W1[k * 256 + m]);
  int m2 = idx >> 8, k2 = idx & 255;          // W2: m in 512, k in 256
  W2T[((m2 >> 7) * 32 + (k2 >> 3)) * 1024 + (m2 & 127) * 8 + (k2 & 7)] = f2bf(W2[k2 * 512 + m2]);
}

// ---------- fp32 [R,K] row-major -> tiled bf16 (RB=128), via LDS transpose ----------
__global__ __launch_bounds__(256) void tile_cvt(const float* __restrict__ src,
                                                ushort_t* __restrict__ dst, const int K) {
  __shared__ __align__(16) ushort_t ls[33024];  // 32 chunks * 129 * 8 ushorts
  const int t = threadIdx.x;
  const int rb = blockIdx.y, cb = blockIdx.x;
  const long sbase = (long)rb * 128 * K + cb * 256;
#pragma unroll 4
  for (int i = 0; i < 32; ++i) {
    int flat = i * 256 + t;                 // float4 slot in 128x64
    int row = flat >> 6, kq = flat & 63;    // kq: float4 within row
    float4 v = *(const float4*)(src + sbase + (long)row * K + kq * 4);
    *(uint2*)(ls + ((kq >> 1) * 129 + row) * 8 + (kq & 1) * 4) =
        make_uint2(pk2(v.x, v.y), pk2(v.z, v.w));
  }
  __syncthreads();
  ushort_t* ob = dst + ((long)rb * (K >> 3) + cb * 32) * 1024;  // 64KB contiguous
  const uint4* lv = (const uint4*)ls;
  uint4* ov = (uint4*)ob;
#pragma unroll 4
  for (int i = 0; i < 16; ++i) {
    int o = i * 256 + t;                    // out uint4 idx: kc = o>>7, r = o&127
    ov[o] = lv[(o >> 7) * 129 + (o & 127)];
  }
}

// ---------- GEMM on tiled bf16: C[M,N] = A*B^T (both operands row-block tiled) ----------
// MT x NT block tile, 4 waves 2x2, BK=32, global_load_lds K-loop.
// EPI 2: relu(C+bias[m]) row-sum -> atomicAdd gacc[m]
// EPI 3: fp32 partials, LANE-MAJOR per-tile layout [z][tile][32768]:
//        slot = (((w*MF+fm)*NF+fn)*4+r)*64 + lane  -> wave writes 32KB contiguous
// EPI 4: direct tiled-bf16 store (RB=256 layout over [M rows, N k])
template<int MT, int NT, int EPI>
__global__ __launch_bounds__(256, 2)
void gemm_t(const ushort_t* __restrict__ A, const ushort_t* __restrict__ B,
            const float* __restrict__ bias, float* __restrict__ Cf,
            float* __restrict__ gacc, const int K, const int N) {
  constexpr int MF = MT / 32, NF = NT / 32;
  constexpr int nA = MT / 64, nB = NT / 64;  // 16B chunks per thread per K-tile
  __shared__ __align__(16) ushort_t Als[MT * 32];
  __shared__ __align__(16) ushort_t Bls[NT * 32];

  const int t = threadIdx.x;
  const int lane = t & 63, w = t >> 6;
  const int wm = w >> 1, wn = w & 1;
  const int ml = lane & 15, quad = lane >> 4;
  const int m0 = blockIdx.y * MT, n0 = blockIdx.x * NT;
  const int Kper = K / gridDim.z, kbeg = blockIdx.z * Kper;

  const char* Ag = (const char*)(A + ((long)((m0 / MT) * (K >> 3) + (kbeg >> 3)) * MT) * 8);
  const char* Bg = (const char*)(B + ((long)((n0 / NT) * (K >> 3) + (kbeg >> 3)) * NT) * 8);

  floatx4 acc[MF][NF] = {};
  const int iters = Kper >> 5;
  for (int it = 0; it < iters; ++it) {
    __syncthreads();                 // prior iter's LDS reads complete
#pragma unroll
    for (int c = 0; c < nA; ++c)
      gl_lds16(Ag + c * 4096 + t * 16, (char*)Als + c * 4096 + t * 16);
#pragma unroll
    for (int c = 0; c < nB; ++c)
      gl_lds16(Bg + c * 4096 + t * 16, (char*)Bls + c * 4096 + t * 16);
    Ag += MT * 64; Bg += NT * 64;
    __syncthreads();                 // drains vmcnt -> LDS tile ready

    short8 av[MF], bv[NF];
#pragma unroll
    for (int f = 0; f < MF; ++f)
      av[f] = *(const short8*)(Als + (quad * MT + wm * (MT / 2) + f * 16 + ml) * 8);
#pragma unroll
    for (int f = 0; f < NF; ++f)
      bv[f] = *(const short8*)(Bls + (quad * NT + wn * (NT / 2) + f * 16 + ml) * 8);
#pragma unroll
    for (int fm = 0; fm < MF; ++fm)
#pragma unroll
      for (int fn = 0; fn < NF; ++fn)
        acc[fm][fn] = __builtin_amdgcn_mfma_f32_16x16x32_bf16(av[fm], bv[fn], acc[fm][fn], 0, 0, 0);
  }

  if constexpr (EPI == 2) {
#pragma unroll
    for (int fm = 0; fm < MF; ++fm) {
      int rowb = m0 + wm * (MT / 2) + fm * 16 + quad * 4;
#pragma unroll
      for (int r = 0; r < 4; ++r) {
        float bb = bias[rowb + r];
        float s = 0.f;
#pragma unroll
        for (int fn = 0; fn < NF; ++fn)
          s += fmaxf(acc[fm][fn][r] + bb, 0.f);
        s += __shfl_xor(s, 1);
        s += __shfl_xor(s, 2);
        s += __shfl_xor(s, 4);
        s += __shfl_xor(s, 8);
        if (ml == 0) atomicAdd(gacc + rowb + r, s);
      }
    }
  } else if constexpr (EPI == 3) {
    // lane-major contiguous partial store: wave w writes a 32KB contiguous run
    const int tv = (NT == 256) ? blockIdx.y : blockIdx.x;   // the varying tile dim
    float* base = Cf + ((long)blockIdx.z * 64 + tv) * 32768 + (w * MF * NF * 4) * 64 + lane;
#pragma unroll
    for (int fm = 0; fm < MF; ++fm)
#pragma unroll
      for (int fn = 0; fn < NF; ++fn)
#pragma unroll
        for (int r = 0; r < 4; ++r)
          base[((fm * NF + fn) * 4 + r) * 64] = acc[fm][fn][r];
  } else {
    // EPI 4: direct tiled-bf16 (RB=256 over [M rows, N k])
    ushort_t* C = (ushort_t*)Cf;
#pragma unroll
    for (int fm = 0; fm < MF; ++fm)
#pragma unroll
      for (int fn = 0; fn < NF; ++fn) {
        int gm = m0 + wm * (MT / 2) + fm * 16 + quad * 4;
        int gn = n0 + wn * (NT / 2) + fn * 16 + ml;
        long ob = (long)(gn >> 3) * 2048 + (gn & 7);
#pragma unroll
        for (int r = 0; r < 4; ++r)
          C[ob + (long)(gm + r) * 8] = f2bf(acc[fm][fn][r]);
      }
  }
}

// ---------- reduce for L1b: partials(MT=256,NT=128, tiles=x) -> h1T tiled RB=256 ----------
__global__ void reduce_L1b(const float* __restrict__ p, ushort_t* __restrict__ h1T,
                           const float* __restrict__ bias) {
  long i = (long)blockIdx.x * 256 + threadIdx.x;   // 524288 threads, uint2 out each
  long o = i * 4;                                  // tiled-linear ushort index
  int j0 = (int)(o & 7);                           // 0 or 4
  int row = (int)((o >> 3) & 255);
  int kc = (int)(o >> 11);                         // [0,1024)
  int k0 = kc * 8 + j0;                            // global n in [0,8192)
  int tx = k0 >> 7, c0 = k0 & 127;
  // producer MF=8, NF=4
  int wm = row >> 7, fm = (row >> 4) & 7, quad = (row >> 2) & 3, r = row & 3;
  int wn = c0 >> 6, fn = (c0 >> 4) & 3, ml = c0 & 15;
  int slot = ((((wm * 2 + wn) * 8 + fm) * 4 + fn) * 4 + r) * 64 + quad * 16 + ml;
  const float* src = p + (long)tx * 32768 + slot;
  float4 s = *(const float4*)src;
  for (int z = 1; z < 8; ++z) {
    float4 b = *(const float4*)(src + (long)z * 2097152);
    s.x += b.x; s.y += b.y; s.z += b.z; s.w += b.w;
  }
  float bb = bias[row];
  s.x = fmaxf(s.x + bb, 0.f); s.y = fmaxf(s.y + bb, 0.f);
  s.z = fmaxf(s.z + bb, 0.f); s.w = fmaxf(s.w + bb, 0.f);
  *(uint2*)(h1T + o) = make_uint2(pk2(s.x, s.y), pk2(s.z, s.w));
}

// ---------- reduce for L2a: partials(MT=128,NT=256, tiles=y) -> P_t tiled RB=128 ----------
__global__ void reduce_L2a(const float* __restrict__ p, ushort_t* __restrict__ P_t) {
  long i = (long)blockIdx.x * 256 + threadIdx.x;   // 524288 threads
  long o = i * 4;
  int j0 = (int)(o & 7);
  int row = (int)((o >> 3) & 127);                 // row within 128-block
  int kc = (int)((o >> 10) & 31);                  // [0,32)
  int ty = (int)(o >> 15);                         // [0,64)
  int k0 = kc * 8 + j0;                            // [0,256)
  // producer MF=4, NF=8
  int wm = row >> 6, fm = (row >> 4) & 3, quad = (row >> 2) & 3, r = row & 3;
  int wn = k0 >> 7, fn = (k0 >> 4) & 7, ml = k0 & 15;
  int slot = ((((wm * 2 + wn) * 4 + fm) * 8 + fn) * 4 + r) * 64 + quad * 16 + ml;
  const float* src = p + (long)ty * 32768 + slot;
  float4 s = *(const float4*)src;
  for (int z = 1; z < 8; ++z) {
    float4 b = *(const float4*)(src + (long)z * 2097152);
    s.x += b.x; s.y += b.y; s.z += b.z; s.w += b.w;
  }
  *(uint2*)(P_t + o) = make_uint2(pk2(s.x, s.y), pk2(s.z, s.w));
}

// ---------- tail: selu(mean) | fc1 | attention | log_softmax (exact fp32) ----------
__global__ void tail_kernel(const float* __restrict__ gacc, const float* __restrict__ sub_fea,
                            const float* __restrict__ fc1_W, const float* __restrict__ fc1_b,
                            const float* __restrict__ att_W, const float* __restrict__ att_a,
                            const float* __restrict__ att_b, float* __restrict__ out) {
  __shared__ float z[768];
  __shared__ float sc[8];
  __shared__ float alpha[8];
  __shared__ float outsh[10];
  const int t = threadIdx.x;  // 256 threads

  for (int j = t; j < 512; j += 256) {
    float x = gacc[j] * (1.0f / 8192.0f);
    const float scale = 1.0507009873554805f, al = 1.6732632423543772f;
    z[j] = x > 0.f ? scale * x : scale * al * (expf(x) - 1.0f);
  }
  {
    float a = fc1_b[t];
    for (int i = 0; i < 128; ++i) a += sub_fea[i] * fc1_W[i * 256 + t];
    z[512 + t] = a;
  }
  if (t < 10) outsh[t] = 0.f;
  __syncthreads();

  {
    int h = t >> 5, ln = t & 31;
    float p = 0.f;
    for (int i = ln; i < 768; i += 32) p += z[i] * att_a[h * 768 + i];
    for (int m = 16; m; m >>= 1) p += __shfl_down(p, m, 32);
    if (ln == 0) sc[h] = p;
  }
  __syncthreads();
  if (t == 0) {
    float mx = sc[0];
    for (int h = 1; h < 8; ++h) mx = fmaxf(mx, sc[h]);
    float s = 0.f, e[8];
    for (int h = 0; h < 8; ++h) { e[h] = expf(sc[h] - mx); s += e[h]; }
    for (int h = 0; h < 8; ++h) alpha[h] = e[h] / s;
  }
  __syncthreads();

  float p[10];
#pragma unroll
  for (int o = 0; o < 10; ++o) p[o] = 0.f;
  for (int i = t; i < 768; i += 256) {
    float zi = z[i];
    for (int h = 0; h < 8; ++h) {
      float za = zi * alpha[h];
      const float* wp = att_W + (h * 768 + i) * 10;
#pragma unroll
      for (int o = 0; o < 10; ++o) p[o] += za * wp[o];
    }
  }
#pragma unroll
  for (int o = 0; o < 10; ++o) atomicAdd(&outsh[o], p[o]);
  __syncthreads();
  if (t == 0) {
    float v[10], mx = -1e30f;
    for (int o = 0; o < 10; ++o) { v[o] = outsh[o] + att_b[o]; mx = fmaxf(mx, v[o]); }
    float s = 0.f;
    for (int o = 0; o < 10; ++o) s += expf(v[o] - mx);
    float lse = logf(s) + mx;
    for (int o = 0; o < 10; ++o) out[o] = v[o] - lse;
  }
}

// ---------- launch ----------
extern "C" void kernel_launch(void* const* d_in, const int* in_sizes, int n_in,
                              void* d_out, int out_size, void* d_ws, size_t ws_size,
                              hipStream_t stream) {
  const float* x       = (const float*)d_in[0];   // [8192,512]
  const float* adj     = (const float*)d_in[1];   // [8192,8192]
  const float* sub_fea = (const float*)d_in[2];   // [1,128]
  const float* gc1_W   = (const float*)d_in[3];   // [512,256]
  const float* gc1_b   = (const float*)d_in[4];   // [256]
  const float* gc2_W   = (const float*)d_in[5];   // [256,512]
  const float* gc2_b   = (const float*)d_in[6];   // [512]
  const float* fc1_W   = (const float*)d_in[7];   // [128,256]
  const float* fc1_b   = (const float*)d_in[8];   // [256]
  const float* att_W   = (const float*)d_in[9];   // [8,768,10]
  const float* att_a   = (const float*)d_in[10];  // [8,768]
  const float* att_b   = (const float*)d_in[11];  // [10]
  float* out = (float*)d_out;

  const size_t MB = 1u << 20;
  char* ws = (char*)d_ws;
  size_t off = 0;
  ushort_t* adjT = (ushort_t*)(ws + off); off += 128 * MB;  // tiled bf16 adj
  ushort_t* xT   = (ushort_t*)(ws + off); off += 8 * MB;    // tiled bf16 x
  ushort_t* t1T  = (ushort_t*)(ws + off); off += 4 * MB;    // [256,8192] tiled RB=256
  ushort_t* h1T  = (ushort_t*)(ws + off); off += 4 * MB;    // [256,8192] tiled RB=256
  ushort_t* P_t  = (ushort_t*)(ws + off); off += 4 * MB;    // [8192,256] tiled RB=128
  float*    part = (float*)   (ws + off); off += 64 * MB;   // [8][64][32768] fp32 lane-major
  ushort_t* W1T  = (ushort_t*)(ws + off); off += 262144;
  ushort_t* W2T  = (ushort_t*)(ws + off); off += 262144;
  float*    gacc = (float*)   (ws + off);

  hipMemsetAsync(gacc, 0, 512 * sizeof(float), stream);
  prep_t<<<512, 256, 0, stream>>>(gc1_W, gc2_W, W1T, W2T);

  // tiled bf16 conversions (adj serves both L1b-B and L2a-A)
  tile_cvt<<<dim3(32, 64), 256, 0, stream>>>(adj, adjT, 8192);
  tile_cvt<<<dim3(2, 64), 256, 0, stream>>>(x, xT, 512);

  // L1a: t1T[256,8192] = W1T * x^T, z=1, direct tiled-bf16 epilogue (no partials)
  gemm_t<128, 128, 4><<<dim3(64, 2, 1), 256, 0, stream>>>(
      W1T, xT, nullptr, (float*)t1T, nullptr, 512, 8192);

  // L1b: s1T[256,8192] = t1T * adj^T, 256x128 tile, adj read once, split-K=8
  gemm_t<256, 128, 3><<<dim3(64, 1, 8), 256, 0, stream>>>(
      t1T, adjT, nullptr, part, nullptr, 8192, 8192);
  reduce_L1b<<<2048, 256, 0, stream>>>(part, h1T, gc1_b);

  // L2a: P[8192,256] = adj * h1, 128x256 tile, adj read once, split-K=8
  gemm_t<128, 256, 3><<<dim3(1, 64, 8), 256, 0, stream>>>(
      adjT, h1T, nullptr, part, nullptr, 8192, 256);
  reduce_L2a<<<2048, 256, 0, stream>>>(part, P_t);

  // L2b: t2T[512,8192] = W2T * P^T ; relu(+gc2_b) row-sum -> gacc
  gemm_t<128, 128, 2><<<dim3(64, 4, 1), 256, 0, stream>>>(
      W2T, P_t, gc2_b, nullptr, gacc, 256, 8192);

  tail_kernel<<<1, 256, 0, stream>>>(gacc, sub_fea, fc1_W, fc1_b, att_W, att_a, att_b, out);
}

// Round 6
// 615.619 us; speedup vs baseline: 1.0465x; 1.0465x over previous
//
#include <hip/hip_runtime.h>

typedef __attribute__((ext_vector_type(8))) short short8;
typedef __attribute__((ext_vector_type(4))) float floatx4;
typedef unsigned short ushort_t;
typedef unsigned int u32;

// ---------- helpers ----------
__device__ __forceinline__ ushort_t f2bf(float x) {
  union { float f; unsigned int u; } v; v.f = x;
  unsigned int u = v.u;
  return (ushort_t)((u + 0x7FFFu + ((u >> 16) & 1u)) >> 16);  // RNE
}
__device__ __forceinline__ unsigned int pk2(float a, float b) {
  return (unsigned int)f2bf(a) | ((unsigned int)f2bf(b) << 16);
}
__device__ __forceinline__ float bf_lo(u32 u) {
  union { u32 u; float f; } v; v.u = u << 16; return v.f;
}
__device__ __forceinline__ float bf_hi(u32 u) {
  union { u32 u; float f; } v; v.u = u & 0xFFFF0000u; return v.f;
}
// async global->LDS, 16B per lane (dest = wave-uniform base + lane*16)
__device__ __forceinline__ void gl_lds16(const void* g, void* l) {
  __builtin_amdgcn_global_load_lds(
      (const __attribute__((address_space(1))) u32*)g,
      (__attribute__((address_space(3))) u32*)l, 16, 0, 0);
}

// Tiled layout, RB in {128,256}:  T[rb][kc][r][j],  element (row,k) at
//   ((row/RB)*(K/8) + k/8)*RB*8 + (row%RB)*8 + (k%8)
// One block's K-tile (32 k, RB rows) is RB*64 bytes CONTIGUOUS and identical
// to the LDS quad-major layout -> straight global_load_lds copy.

// ---------- prep: weights -> tiled bf16 (RB=128) ----------
__global__ void prep_t(const float* __restrict__ W1, const float* __restrict__ W2,
                       ushort_t* __restrict__ W1T, ushort_t* __restrict__ W2T) {
  int idx = blockIdx.x * 256 + threadIdx.x;   // 0 .. 131071
  int m = idx >> 9, k = idx & 511;            // W1: m in 256, k in 512
  W1T[((m >> 7) * 64 + (k >> 3)) * 1024 + (m & 127) * 8 + (k & 7)] = f2bf(W1[k * 256 + m]);
  int m2 = idx >> 8, k2 = idx & 255;          // W2: m in 512, k in 256
  W2T[((m2 >> 7) * 32 + (k2 >> 3)) * 1024 + (m2 & 127) * 8 + (k2 & 7)] = f2bf(W2[k2 * 512 + m2]);
}

// ---------- fp32 [R,K] row-major -> tiled bf16 (RB=128), via LDS transpose ----------
__global__ __launch_bounds__(256) void tile_cvt(const float* __restrict__ src,
                                                ushort_t* __restrict__ dst, const int K) {
  __shared__ __align__(16) ushort_t ls[33024];  // 32 chunks * 129 * 8 ushorts
  const int t = threadIdx.x;
  const int rb = blockIdx.y, cb = blockIdx.x;
  const long sbase = (long)rb * 128 * K + cb * 256;
#pragma unroll 4
  for (int i = 0; i < 32; ++i) {
    int flat = i * 256 + t;                 // float4 slot in 128x64
    int row = flat >> 6, kq = flat & 63;    // kq: float4 within row
    float4 v = *(const float4*)(src + sbase + (long)row * K + kq * 4);
    *(uint2*)(ls + ((kq >> 1) * 129 + row) * 8 + (kq & 1) * 4) =
        make_uint2(pk2(v.x, v.y), pk2(v.z, v.w));
  }
  __syncthreads();
  ushort_t* ob = dst + ((long)rb * (K >> 3) + cb * 32) * 1024;  // 64KB contiguous
  const uint4* lv = (const uint4*)ls;
  uint4* ov = (uint4*)ob;
#pragma unroll 4
  for (int i = 0; i < 16; ++i) {
    int o = i * 256 + t;                    // out uint4 idx: kc = o>>7, r = o&127
    ov[o] = lv[(o >> 7) * 129 + (o & 127)];
  }
}

// ---------- GEMM on tiled bf16: C = A*B^T, double-buffered LDS K-loop ----------
// MT x NT block tile, 4 waves 2x2, BK=32. One barrier per iter; DMA for tile
// k+1 issued right after the barrier publishing tile k (loads fly during MFMA).
// EPI 2: relu(C+bias[m]) row-sum -> atomicAdd gacc[m]
// EPI 3: bf16 partials, lane-major r-paired u32: tile = [slot][64 lanes],
//        slot = ((w*MF+fm)*NF+fn)*2+rp, value = pk2(acc[2rp], acc[2rp+1])
// EPI 4: direct tiled-bf16 store (RB=256 layout over [M rows, N k])
template<int MT, int NT, int EPI>
__global__ __launch_bounds__(256, 2)
void gemm_t(const ushort_t* __restrict__ A, const ushort_t* __restrict__ B,
            const float* __restrict__ bias, float* __restrict__ Cf,
            float* __restrict__ gacc, const int K, const int N) {
  constexpr int MF = MT / 32, NF = NT / 32;
  constexpr int nA = MT / 64, nB = NT / 64;  // 16B chunks per thread per K-tile
  __shared__ __align__(16) ushort_t Als[2][MT * 32];
  __shared__ __align__(16) ushort_t Bls[2][NT * 32];

  const int t = threadIdx.x;
  const int lane = t & 63, w = t >> 6;
  const int wm = w >> 1, wn = w & 1;
  const int ml = lane & 15, quad = lane >> 4;
  const int m0 = blockIdx.y * MT, n0 = blockIdx.x * NT;
  const int Kper = K / gridDim.z, kbeg = blockIdx.z * Kper;

  const char* Ag = (const char*)(A + ((long)((m0 / MT) * (K >> 3) + (kbeg >> 3)) * MT) * 8);
  const char* Bg = (const char*)(B + ((long)((n0 / NT) * (K >> 3) + (kbeg >> 3)) * NT) * 8);

  floatx4 acc[MF][NF] = {};
  const int iters = Kper >> 5;

  // prologue: tile 0 -> buffer 0
#pragma unroll
  for (int c = 0; c < nA; ++c)
    gl_lds16(Ag + c * 4096 + t * 16, (char*)Als[0] + c * 4096 + t * 16);
#pragma unroll
  for (int c = 0; c < nB; ++c)
    gl_lds16(Bg + c * 4096 + t * 16, (char*)Bls[0] + c * 4096 + t * 16);
  Ag += MT * 64; Bg += NT * 64;

  for (int it = 0; it < iters; ++it) {
    const int cur = it & 1, nxt = cur ^ 1;
    __syncthreads();   // vmcnt(0) drain: cur tile ready; prior reads of nxt done
    if (it + 1 < iters) {   // issue next tile NOW -> flies during MFMA phase
#pragma unroll
      for (int c = 0; c < nA; ++c)
        gl_lds16(Ag + c * 4096 + t * 16, (char*)Als[nxt] + c * 4096 + t * 16);
#pragma unroll
      for (int c = 0; c < nB; ++c)
        gl_lds16(Bg + c * 4096 + t * 16, (char*)Bls[nxt] + c * 4096 + t * 16);
      Ag += MT * 64; Bg += NT * 64;
    }

    short8 av[MF], bv[NF];
#pragma unroll
    for (int f = 0; f < MF; ++f)
      av[f] = *(const short8*)(&Als[cur][0] + (quad * MT + wm * (MT / 2) + f * 16 + ml) * 8);
#pragma unroll
    for (int f = 0; f < NF; ++f)
      bv[f] = *(const short8*)(&Bls[cur][0] + (quad * NT + wn * (NT / 2) + f * 16 + ml) * 8);
#pragma unroll
    for (int fm = 0; fm < MF; ++fm)
#pragma unroll
      for (int fn = 0; fn < NF; ++fn)
        acc[fm][fn] = __builtin_amdgcn_mfma_f32_16x16x32_bf16(av[fm], bv[fn], acc[fm][fn], 0, 0, 0);
  }

  if constexpr (EPI == 2) {
#pragma unroll
    for (int fm = 0; fm < MF; ++fm) {
      int rowb = m0 + wm * (MT / 2) + fm * 16 + quad * 4;
#pragma unroll
      for (int r = 0; r < 4; ++r) {
        float bb = bias[rowb + r];
        float s = 0.f;
#pragma unroll
        for (int fn = 0; fn < NF; ++fn)
          s += fmaxf(acc[fm][fn][r] + bb, 0.f);
        s += __shfl_xor(s, 1);
        s += __shfl_xor(s, 2);
        s += __shfl_xor(s, 4);
        s += __shfl_xor(s, 8);
        if (ml == 0) atomicAdd(gacc + rowb + r, s);
      }
    }
  } else if constexpr (EPI == 3) {
    // bf16 r-paired lane-major partials: tile = MF*NF*8 slots x 64 lanes (u32)
    const int tv = (NT == 256) ? blockIdx.y : blockIdx.x;   // the varying tile dim
    u32* base = (u32*)Cf + ((long)blockIdx.z * 64 + tv) * (MF * NF * 8 * 64)
                + (w * MF * NF * 2) * 64 + lane;
#pragma unroll
    for (int fm = 0; fm < MF; ++fm)
#pragma unroll
      for (int fn = 0; fn < NF; ++fn)
#pragma unroll
        for (int rp = 0; rp < 2; ++rp)
          base[((fm * NF + fn) * 2 + rp) * 64] =
              pk2(acc[fm][fn][2 * rp], acc[fm][fn][2 * rp + 1]);
  } else {
    // EPI 4: direct tiled-bf16 (RB=256 over [M rows, N k])
    ushort_t* C = (ushort_t*)Cf;
#pragma unroll
    for (int fm = 0; fm < MF; ++fm)
#pragma unroll
      for (int fn = 0; fn < NF; ++fn) {
        int gm = m0 + wm * (MT / 2) + fm * 16 + quad * 4;
        int gn = n0 + wn * (NT / 2) + fn * 16 + ml;
        long ob = (long)(gn >> 3) * 2048 + (gn & 7);
#pragma unroll
        for (int r = 0; r < 4; ++r)
          C[ob + (long)(gm + r) * 8] = f2bf(acc[fm][fn][r]);
      }
  }
}

// ---------- reduce L1b: bf16 partials (MT=256,NT=128,MF=8,NF=4, tile=x) -> h1T (RB=256) ----------
__global__ void reduce_L1b(const u32* __restrict__ p, ushort_t* __restrict__ h1T,
                           const float* __restrict__ bias) {
  long i = (long)blockIdx.x * 256 + threadIdx.x;   // 524288 threads, uint2 out each
  long o = i * 4;                                  // tiled-linear ushort index
  int row = (int)((o >> 3) & 255);
  int k0 = (int)((o >> 11) << 3) + (int)(o & 7);   // global n in [0,8192)
  int tx = k0 >> 7, c0 = k0 & 127;
  // producer decode
  int wm = row >> 7, fm = (row >> 4) & 7, quad = (row >> 2) & 3, r = row & 3;
  int wn = c0 >> 6, fn = (c0 >> 4) & 3, ml = c0 & 15;   // ml % 4 == 0
  int slot = (((wm * 2 + wn) * 8 + fm) * 4 + fn) * 2 + (r >> 1);
  const u32* src = p + (long)tx * 16384 + slot * 64 + quad * 16 + ml;
  const bool hi = r & 1;
  float s0 = 0, s1 = 0, s2 = 0, s3 = 0;
  for (int z = 0; z < 8; ++z) {
    uint4 v = *(const uint4*)(src + (long)z * 1048576);
    if (hi) { s0 += bf_hi(v.x); s1 += bf_hi(v.y); s2 += bf_hi(v.z); s3 += bf_hi(v.w); }
    else    { s0 += bf_lo(v.x); s1 += bf_lo(v.y); s2 += bf_lo(v.z); s3 += bf_lo(v.w); }
  }
  float bb = bias[row];
  s0 = fmaxf(s0 + bb, 0.f); s1 = fmaxf(s1 + bb, 0.f);
  s2 = fmaxf(s2 + bb, 0.f); s3 = fmaxf(s3 + bb, 0.f);
  *(uint2*)(h1T + o) = make_uint2(pk2(s0, s1), pk2(s2, s3));
}

// ---------- reduce L2a: bf16 partials (MT=128,NT=256,MF=4,NF=8, tile=y) -> P_t (RB=128) ----------
__global__ void reduce_L2a(const u32* __restrict__ p, ushort_t* __restrict__ P_t) {
  long i = (long)blockIdx.x * 256 + threadIdx.x;   // 524288 threads
  long o = i * 4;
  int row = (int)((o >> 3) & 127);
  int kc = (int)((o >> 10) & 31);
  int ty = (int)(o >> 15);
  int k0 = kc * 8 + (int)(o & 7);                  // [0,256)
  int wm = row >> 6, fm = (row >> 4) & 3, quad = (row >> 2) & 3, r = row & 3;
  int wn = k0 >> 7, fn = (k0 >> 4) & 7, ml = k0 & 15;   // ml % 4 == 0
  int slot = (((wm * 2 + wn) * 4 + fm) * 8 + fn) * 2 + (r >> 1);
  const u32* src = p + (long)ty * 16384 + slot * 64 + quad * 16 + ml;
  const bool hi = r & 1;
  float s0 = 0, s1 = 0, s2 = 0, s3 = 0;
  for (int z = 0; z < 8; ++z) {
    uint4 v = *(const uint4*)(src + (long)z * 1048576);
    if (hi) { s0 += bf_hi(v.x); s1 += bf_hi(v.y); s2 += bf_hi(v.z); s3 += bf_hi(v.w); }
    else    { s0 += bf_lo(v.x); s1 += bf_lo(v.y); s2 += bf_lo(v.z); s3 += bf_lo(v.w); }
  }
  *(uint2*)(P_t + o) = make_uint2(pk2(s0, s1), pk2(s2, s3));
}

// ---------- tail: selu(mean) | fc1 | attention | log_softmax (exact fp32) ----------
__global__ void tail_kernel(const float* __restrict__ gacc, const float* __restrict__ sub_fea,
                            const float* __restrict__ fc1_W, const float* __restrict__ fc1_b,
                            const float* __restrict__ att_W, const float* __restrict__ att_a,
                            const float* __restrict__ att_b, float* __restrict__ out) {
  __shared__ float z[768];
  __shared__ float sc[8];
  __shared__ float alpha[8];
  __shared__ float outsh[10];
  const int t = threadIdx.x;  // 256 threads

  for (int j = t; j < 512; j += 256) {
    float x = gacc[j] * (1.0f / 8192.0f);
    const float scale = 1.0507009873554805f, al = 1.6732632423543772f;
    z[j] = x > 0.f ? scale * x : scale * al * (expf(x) - 1.0f);
  }
  {
    float a = fc1_b[t];
    for (int i = 0; i < 128; ++i) a += sub_fea[i] * fc1_W[i * 256 + t];
    z[512 + t] = a;
  }
  if (t < 10) outsh[t] = 0.f;
  __syncthreads();

  {
    int h = t >> 5, ln = t & 31;
    float p = 0.f;
    for (int i = ln; i < 768; i += 32) p += z[i] * att_a[h * 768 + i];
    for (int m = 16; m; m >>= 1) p += __shfl_down(p, m, 32);
    if (ln == 0) sc[h] = p;
  }
  __syncthreads();
  if (t == 0) {
    float mx = sc[0];
    for (int h = 1; h < 8; ++h) mx = fmaxf(mx, sc[h]);
    float s = 0.f, e[8];
    for (int h = 0; h < 8; ++h) { e[h] = expf(sc[h] - mx); s += e[h]; }
    for (int h = 0; h < 8; ++h) alpha[h] = e[h] / s;
  }
  __syncthreads();

  float p[10];
#pragma unroll
  for (int o = 0; o < 10; ++o) p[o] = 0.f;
  for (int i = t; i < 768; i += 256) {
    float zi = z[i];
    for (int h = 0; h < 8; ++h) {
      float za = zi * alpha[h];
      const float* wp = att_W + (h * 768 + i) * 10;
#pragma unroll
      for (int o = 0; o < 10; ++o) p[o] += za * wp[o];
    }
  }
#pragma unroll
  for (int o = 0; o < 10; ++o) atomicAdd(&outsh[o], p[o]);
  __syncthreads();
  if (t == 0) {
    float v[10], mx = -1e30f;
    for (int o = 0; o < 10; ++o) { v[o] = outsh[o] + att_b[o]; mx = fmaxf(mx, v[o]); }
    float s = 0.f;
    for (int o = 0; o < 10; ++o) s += expf(v[o] - mx);
    float lse = logf(s) + mx;
    for (int o = 0; o < 10; ++o) out[o] = v[o] - lse;
  }
}

// ---------- launch ----------
extern "C" void kernel_launch(void* const* d_in, const int* in_sizes, int n_in,
                              void* d_out, int out_size, void* d_ws, size_t ws_size,
                              hipStream_t stream) {
  const float* x       = (const float*)d_in[0];   // [8192,512]
  const float* adj     = (const float*)d_in[1];   // [8192,8192]
  const float* sub_fea = (const float*)d_in[2];   // [1,128]
  const float* gc1_W   = (const float*)d_in[3];   // [512,256]
  const float* gc1_b   = (const float*)d_in[4];   // [256]
  const float* gc2_W   = (const float*)d_in[5];   // [256,512]
  const float* gc2_b   = (const float*)d_in[6];   // [512]
  const float* fc1_W   = (const float*)d_in[7];   // [128,256]
  const float* fc1_b   = (const float*)d_in[8];   // [256]
  const float* att_W   = (const float*)d_in[9];   // [8,768,10]
  const float* att_a   = (const float*)d_in[10];  // [8,768]
  const float* att_b   = (const float*)d_in[11];  // [10]
  float* out = (float*)d_out;

  const size_t MB = 1u << 20;
  char* ws = (char*)d_ws;
  size_t off = 0;
  ushort_t* adjT = (ushort_t*)(ws + off); off += 128 * MB;  // tiled bf16 adj
  ushort_t* xT   = (ushort_t*)(ws + off); off += 8 * MB;    // tiled bf16 x
  ushort_t* t1T  = (ushort_t*)(ws + off); off += 4 * MB;    // [256,8192] tiled RB=256
  ushort_t* h1T  = (ushort_t*)(ws + off); off += 4 * MB;    // [256,8192] tiled RB=256
  ushort_t* P_t  = (ushort_t*)(ws + off); off += 4 * MB;    // [8192,256] tiled RB=128
  u32*      part = (u32*)     (ws + off); off += 32 * MB;   // [8][64][16384] bf16-pair partials
  ushort_t* W1T  = (ushort_t*)(ws + off); off += 262144;
  ushort_t* W2T  = (ushort_t*)(ws + off); off += 262144;
  float*    gacc = (float*)   (ws + off);

  hipMemsetAsync(gacc, 0, 512 * sizeof(float), stream);
  prep_t<<<512, 256, 0, stream>>>(gc1_W, gc2_W, W1T, W2T);

  // tiled bf16 conversions (adj serves both L1b-B and L2a-A)
  tile_cvt<<<dim3(32, 64), 256, 0, stream>>>(adj, adjT, 8192);
  tile_cvt<<<dim3(2, 64), 256, 0, stream>>>(x, xT, 512);

  // L1a: t1T[256,8192] = W1T * x^T, z=1, direct tiled-bf16 epilogue
  gemm_t<128, 128, 4><<<dim3(64, 2, 1), 256, 0, stream>>>(
      W1T, xT, nullptr, (float*)t1T, nullptr, 512, 8192);

  // L1b: s1T[256,8192] = t1T * adj^T, 256x128 tile, adj read once, split-K=8
  gemm_t<256, 128, 3><<<dim3(64, 1, 8), 256, 0, stream>>>(
      t1T, adjT, nullptr, (float*)part, nullptr, 8192, 8192);
  reduce_L1b<<<2048, 256, 0, stream>>>(part, h1T, gc1_b);

  // L2a: P[8192,256] = adj * h1, 128x256 tile, adj read once, split-K=8
  gemm_t<128, 256, 3><<<dim3(1, 64, 8), 256, 0, stream>>>(
      adjT, h1T, nullptr, (float*)part, nullptr, 8192, 256);
  reduce_L2a<<<2048, 256, 0, stream>>>(part, P_t);

  // L2b: t2T[512,8192] = W2T * P^T ; relu(+gc2_b) row-sum -> gacc
  gemm_t<128, 128, 2><<<dim3(64, 4, 1), 256, 0, stream>>>(
      W2T, P_t, gc2_b, nullptr, gacc, 256, 8192);

  tail_kernel<<<1, 256, 0, stream>>>(gacc, sub_fea, fc1_W, fc1_b, att_W, att_a, att_b, out);
}

// Round 7
// 588.413 us; speedup vs baseline: 1.0949x; 1.0462x over previous
//
#include <hip/hip_runtime.h>

typedef __attribute__((ext_vector_type(8))) short short8;
typedef __attribute__((ext_vector_type(4))) float floatx4;
typedef unsigned short ushort_t;
typedef unsigned int u32;
typedef unsigned char u8;

// ---------- helpers ----------
__device__ __forceinline__ ushort_t f2bf(float x) {
  union { float f; unsigned int u; } v; v.f = x;
  unsigned int u = v.u;
  return (ushort_t)((u + 0x7FFFu + ((u >> 16) & 1u)) >> 16);  // RNE
}
__device__ __forceinline__ unsigned int pk2(float a, float b) {
  return (unsigned int)f2bf(a) | ((unsigned int)f2bf(b) << 16);
}
__device__ __forceinline__ float bf_lo(u32 u) {
  union { u32 u; float f; } v; v.u = u << 16; return v.f;
}
__device__ __forceinline__ float bf_hi(u32 u) {
  union { u32 u; float f; } v; v.u = u & 0xFFFF0000u; return v.f;
}
// pack 4 floats -> 4 fp8 e4m3 bytes (HW cvt, OCP format on gfx950)
__device__ __forceinline__ u32 pk4_fp8(float a, float b, float c, float d) {
  int r = __builtin_amdgcn_cvt_pk_fp8_f32(a, b, 0, false);
  r = __builtin_amdgcn_cvt_pk_fp8_f32(c, d, r, true);
  return (u32)r;
}
__device__ __forceinline__ u8 f2fp8(float a) {
  return (u8)(__builtin_amdgcn_cvt_pk_fp8_f32(a, 0.f, 0, false) & 0xFF);
}
// async global->LDS, 16B per lane (dest = wave-uniform base + lane*16)
__device__ __forceinline__ void gl_lds16(const void* g, void* l) {
  __builtin_amdgcn_global_load_lds(
      (const __attribute__((address_space(1))) u32*)g,
      (__attribute__((address_space(3))) u32*)l, 16, 0, 0);
}

// Tiled layout (element size E bytes), RB rows/block: element (row,k) at byte
//   ((row/RB)*(K/8) + k/8)*RB*8*E + (row%RB)*8*E + (k%8)*E
// One 32-k x RB-row K-tile is RB*32*E bytes CONTIGUOUS, matching LDS layout.

// ---------- prep: weights -> tiled bf16 (RB=128) ----------
__global__ void prep_t(const float* __restrict__ W1, const float* __restrict__ W2,
                       ushort_t* __restrict__ W1T, ushort_t* __restrict__ W2T) {
  int idx = blockIdx.x * 256 + threadIdx.x;   // 0 .. 131071
  int m = idx >> 9, k = idx & 511;            // W1: m in 256, k in 512
  W1T[((m >> 7) * 64 + (k >> 3)) * 1024 + (m & 127) * 8 + (k & 7)] = f2bf(W1[k * 256 + m]);
  int m2 = idx >> 8, k2 = idx & 255;          // W2: m in 512, k in 256
  W2T[((m2 >> 7) * 32 + (k2 >> 3)) * 1024 + (m2 & 127) * 8 + (k2 & 7)] = f2bf(W2[k2 * 512 + m2]);
}

// ---------- fp32 [R,K] row-major -> tiled bf16 (RB=128), via LDS transpose ----------
__global__ __launch_bounds__(256) void tile_cvt(const float* __restrict__ src,
                                                ushort_t* __restrict__ dst, const int K) {
  __shared__ __align__(16) ushort_t ls[33024];  // 32 chunks * 129 * 8 ushorts
  const int t = threadIdx.x;
  const int rb = blockIdx.y, cb = blockIdx.x;
  const long sbase = (long)rb * 128 * K + cb * 256;
#pragma unroll 4
  for (int i = 0; i < 32; ++i) {
    int flat = i * 256 + t;
    int row = flat >> 6, kq = flat & 63;
    float4 v = *(const float4*)(src + sbase + (long)row * K + kq * 4);
    *(uint2*)(ls + ((kq >> 1) * 129 + row) * 8 + (kq & 1) * 4) =
        make_uint2(pk2(v.x, v.y), pk2(v.z, v.w));
  }
  __syncthreads();
  ushort_t* ob = dst + ((long)rb * (K >> 3) + cb * 32) * 1024;
  const uint4* lv = (const uint4*)ls;
  uint4* ov = (uint4*)ob;
#pragma unroll 4
  for (int i = 0; i < 16; ++i) {
    int o = i * 256 + t;
    ov[o] = lv[(o >> 7) * 129 + (o & 127)];
  }
}

// ---------- fp32 adj -> tiled fp8 e4m3 (RB=128), scaled x8192, via LDS ----------
// block = 128 rows x 256 k; grid (32, 64) for [8192,8192].
__global__ __launch_bounds__(256) void tile_cvt8(const float* __restrict__ src,
                                                 u8* __restrict__ dst) {
  __shared__ __align__(16) u32 lsu[32 * 260];   // 32 chunks, stride 260 u32 (1040 B)
  const int t = threadIdx.x;
  const int rb = blockIdx.y, cb = blockIdx.x;
  const long sbase = (long)rb * 128 * 8192 + cb * 256;
#pragma unroll 4
  for (int i = 0; i < 32; ++i) {
    int flat = i * 256 + t;
    int row = flat >> 6, kq = flat & 63;
    float4 v = *(const float4*)(src + sbase + (long)row * 8192 + kq * 4);
    lsu[(kq >> 1) * 260 + row * 2 + (kq & 1)] =
        pk4_fp8(v.x * 8192.f, v.y * 8192.f, v.z * 8192.f, v.w * 8192.f);
  }
  __syncthreads();
  // out: 32 KB contiguous per block
  u8* ob = dst + ((long)rb * 1024 + cb * 32) * 1024;
  const uint4* lv = (const uint4*)lsu;
  uint4* ov = (uint4*)ob;
#pragma unroll 4
  for (int i = 0; i < 8; ++i) {
    int o = i * 256 + t;                        // kc = o>>6, r4 = o&63
    ov[o] = lv[(o >> 6) * 65 + (o & 63)];
  }
}

// ---------- bf16 GEMM on tiled operands: C = A*B^T, double-buffered DMA ----------
// EPI 2: relu(C+bias[m]) row-sum -> atomicAdd gacc[m]
// EPI 5: quantize C -> fp8 e4m3, tiled RB=256 over [M rows, N k]
template<int MT, int NT, int EPI>
__global__ __launch_bounds__(256, 2)
void gemm_t(const ushort_t* __restrict__ A, const ushort_t* __restrict__ B,
            const float* __restrict__ bias, void* __restrict__ Cv,
            float* __restrict__ gacc, const int K, const int N) {
  constexpr int MF = MT / 32, NF = NT / 32;
  constexpr int nA = MT / 64, nB = NT / 64;
  __shared__ __align__(16) ushort_t Als[2][MT * 32];
  __shared__ __align__(16) ushort_t Bls[2][NT * 32];

  const int t = threadIdx.x;
  const int lane = t & 63, w = t >> 6;
  const int wm = w >> 1, wn = w & 1;
  const int ml = lane & 15, quad = lane >> 4;
  const int m0 = blockIdx.y * MT, n0 = blockIdx.x * NT;
  const int Kper = K / gridDim.z, kbeg = blockIdx.z * Kper;

  const char* Ag = (const char*)(A + ((long)((m0 / MT) * (K >> 3) + (kbeg >> 3)) * MT) * 8);
  const char* Bg = (const char*)(B + ((long)((n0 / NT) * (K >> 3) + (kbeg >> 3)) * NT) * 8);

  floatx4 acc[MF][NF] = {};
  const int iters = Kper >> 5;

#pragma unroll
  for (int c = 0; c < nA; ++c)
    gl_lds16(Ag + c * 4096 + t * 16, (char*)Als[0] + c * 4096 + t * 16);
#pragma unroll
  for (int c = 0; c < nB; ++c)
    gl_lds16(Bg + c * 4096 + t * 16, (char*)Bls[0] + c * 4096 + t * 16);
  Ag += MT * 64; Bg += NT * 64;

  for (int it = 0; it < iters; ++it) {
    const int cur = it & 1, nxt = cur ^ 1;
    __syncthreads();
    if (it + 1 < iters) {
#pragma unroll
      for (int c = 0; c < nA; ++c)
        gl_lds16(Ag + c * 4096 + t * 16, (char*)Als[nxt] + c * 4096 + t * 16);
#pragma unroll
      for (int c = 0; c < nB; ++c)
        gl_lds16(Bg + c * 4096 + t * 16, (char*)Bls[nxt] + c * 4096 + t * 16);
      Ag += MT * 64; Bg += NT * 64;
    }
    short8 av[MF], bv[NF];
#pragma unroll
    for (int f = 0; f < MF; ++f)
      av[f] = *(const short8*)(&Als[cur][0] + (quad * MT + wm * (MT / 2) + f * 16 + ml) * 8);
#pragma unroll
    for (int f = 0; f < NF; ++f)
      bv[f] = *(const short8*)(&Bls[cur][0] + (quad * NT + wn * (NT / 2) + f * 16 + ml) * 8);
#pragma unroll
    for (int fm = 0; fm < MF; ++fm)
#pragma unroll
      for (int fn = 0; fn < NF; ++fn)
        acc[fm][fn] = __builtin_amdgcn_mfma_f32_16x16x32_bf16(av[fm], bv[fn], acc[fm][fn], 0, 0, 0);
  }

  if constexpr (EPI == 2) {
#pragma unroll
    for (int fm = 0; fm < MF; ++fm) {
      int rowb = m0 + wm * (MT / 2) + fm * 16 + quad * 4;
#pragma unroll
      for (int r = 0; r < 4; ++r) {
        float bb = bias[rowb + r];
        float s = 0.f;
#pragma unroll
        for (int fn = 0; fn < NF; ++fn)
          s += fmaxf(acc[fm][fn][r] + bb, 0.f);
        s += __shfl_xor(s, 1);
        s += __shfl_xor(s, 2);
        s += __shfl_xor(s, 4);
        s += __shfl_xor(s, 8);
        if (ml == 0) atomicAdd(gacc + rowb + r, s);
      }
    }
  } else {
    // EPI 5: fp8 tiled RB=256 over [M=256 rows, N k]
    u8* C8 = (u8*)Cv;
#pragma unroll
    for (int fm = 0; fm < MF; ++fm)
#pragma unroll
      for (int fn = 0; fn < NF; ++fn) {
        int gm = m0 + wm * (MT / 2) + fm * 16 + quad * 4;
        int gn = n0 + wn * (NT / 2) + fn * 16 + ml;
        long ob = (long)(gn >> 3) * 2048 + (gn & 7);
#pragma unroll
        for (int r = 0; r < 4; ++r)
          C8[ob + (long)(gm + r) * 8] = f2fp8(acc[fm][fn][r]);
      }
  }
}

// ---------- fp8 GEMM on tiled operands: C = A*B^T, double-buffered DMA ----------
// Writes bf16-pair lane-major partials at split-K z offset (same layout as r6).
template<int MT, int NT>
__global__ __launch_bounds__(256, 2)
void gemm8_t(const u8* __restrict__ A, const u8* __restrict__ B,
             u32* __restrict__ Cp, const int K) {
  constexpr int MF = MT / 32, NF = NT / 32;
  constexpr int nA = MT / 128, nB = NT / 128;   // 4KB DMA chunks per K-tile
  __shared__ __align__(16) u8 Als[2][MT * 32];
  __shared__ __align__(16) u8 Bls[2][NT * 32];

  const int t = threadIdx.x;
  const int lane = t & 63, w = t >> 6;
  const int wm = w >> 1, wn = w & 1;
  const int ml = lane & 15, quad = lane >> 4;
  const int m0 = blockIdx.y * MT, n0 = blockIdx.x * NT;
  const int Kper = K / gridDim.z, kbeg = blockIdx.z * Kper;

  const u8* Ag = A + ((long)((m0 / MT) * (K >> 3) + (kbeg >> 3))) * (MT * 8);
  const u8* Bg = B + ((long)((n0 / NT) * (K >> 3) + (kbeg >> 3))) * (NT * 8);

  floatx4 acc[MF][NF] = {};
  const int iters = Kper >> 5;

#pragma unroll
  for (int c = 0; c < nA; ++c)
    gl_lds16(Ag + c * 4096 + t * 16, &Als[0][0] + c * 4096 + t * 16);
#pragma unroll
  for (int c = 0; c < nB; ++c)
    gl_lds16(Bg + c * 4096 + t * 16, &Bls[0][0] + c * 4096 + t * 16);
  Ag += MT * 32; Bg += NT * 32;

  for (int it = 0; it < iters; ++it) {
    const int cur = it & 1, nxt = cur ^ 1;
    __syncthreads();
    if (it + 1 < iters) {
#pragma unroll
      for (int c = 0; c < nA; ++c)
        gl_lds16(Ag + c * 4096 + t * 16, &Als[nxt][0] + c * 4096 + t * 16);
#pragma unroll
      for (int c = 0; c < nB; ++c)
        gl_lds16(Bg + c * 4096 + t * 16, &Bls[nxt][0] + c * 4096 + t * 16);
      Ag += MT * 32; Bg += NT * 32;
    }
    long av[MF], bv[NF];
#pragma unroll
    for (int f = 0; f < MF; ++f)
      av[f] = *(const long*)(&Als[cur][0] + (quad * MT + wm * (MT / 2) + f * 16 + ml) * 8);
#pragma unroll
    for (int f = 0; f < NF; ++f)
      bv[f] = *(const long*)(&Bls[cur][0] + (quad * NT + wn * (NT / 2) + f * 16 + ml) * 8);
#pragma unroll
    for (int fm = 0; fm < MF; ++fm)
#pragma unroll
      for (int fn = 0; fn < NF; ++fn)
        acc[fm][fn] = __builtin_amdgcn_mfma_f32_16x16x32_fp8_fp8(av[fm], bv[fn], acc[fm][fn], 0, 0, 0);
  }

  const int tv = (NT == 256) ? blockIdx.y : blockIdx.x;
  u32* base = Cp + ((long)blockIdx.z * 64 + tv) * (MF * NF * 8 * 64)
              + (w * MF * NF * 2) * 64 + lane;
#pragma unroll
  for (int fm = 0; fm < MF; ++fm)
#pragma unroll
    for (int fn = 0; fn < NF; ++fn)
#pragma unroll
      for (int rp = 0; rp < 2; ++rp)
        base[((fm * NF + fn) * 2 + rp) * 64] =
            pk2(acc[fm][fn][2 * rp], acc[fm][fn][2 * rp + 1]);
}

// ---------- reduce L1b: partials (MF=8,NF=4, tile=x) -> h1T fp8 (RB=256, x256) ----------
__global__ void reduce_L1b(const u32* __restrict__ p, u8* __restrict__ h1T8,
                           const float* __restrict__ bias) {
  long i = (long)blockIdx.x * 256 + threadIdx.x;   // 524288 threads
  long o = i * 4;                                  // tiled byte index
  int row = (int)((o >> 3) & 255);
  int k0 = (int)((o >> 11) << 3) + (int)(o & 7);   // global n in [0,8192)
  int tx = k0 >> 7, c0 = k0 & 127;
  int wm = row >> 7, fm = (row >> 4) & 7, quad = (row >> 2) & 3, r = row & 3;
  int wn = c0 >> 6, fn = (c0 >> 4) & 3, ml = c0 & 15;
  int slot = (((wm * 2 + wn) * 8 + fm) * 4 + fn) * 2 + (r >> 1);
  const u32* src = p + (long)tx * 16384 + slot * 64 + quad * 16 + ml;
  const bool hi = r & 1;
  float s0 = 0, s1 = 0, s2 = 0, s3 = 0;
  for (int z = 0; z < 8; ++z) {
    uint4 v = *(const uint4*)(src + (long)z * 1048576);
    if (hi) { s0 += bf_hi(v.x); s1 += bf_hi(v.y); s2 += bf_hi(v.z); s3 += bf_hi(v.w); }
    else    { s0 += bf_lo(v.x); s1 += bf_lo(v.y); s2 += bf_lo(v.z); s3 += bf_lo(v.w); }
  }
  const float si = 1.f / 8192.f, so = 256.f;       // unscale adj, rescale h1 for fp8
  float bb = bias[row];
  s0 = fmaxf(s0 * si + bb, 0.f) * so; s1 = fmaxf(s1 * si + bb, 0.f) * so;
  s2 = fmaxf(s2 * si + bb, 0.f) * so; s3 = fmaxf(s3 * si + bb, 0.f) * so;
  *(u32*)(h1T8 + o) = pk4_fp8(s0, s1, s2, s3);
}

// ---------- reduce L2a: partials (MF=4,NF=8, tile=y) -> P_t bf16 (RB=128) ----------
__global__ void reduce_L2a(const u32* __restrict__ p, ushort_t* __restrict__ P_t) {
  long i = (long)blockIdx.x * 256 + threadIdx.x;
  long o = i * 4;
  int row = (int)((o >> 3) & 127);
  int kc = (int)((o >> 10) & 31);
  int ty = (int)(o >> 15);
  int k0 = kc * 8 + (int)(o & 7);
  int wm = row >> 6, fm = (row >> 4) & 3, quad = (row >> 2) & 3, r = row & 3;
  int wn = k0 >> 7, fn = (k0 >> 4) & 7, ml = k0 & 15;
  int slot = (((wm * 2 + wn) * 4 + fm) * 8 + fn) * 2 + (r >> 1);
  const u32* src = p + (long)ty * 16384 + slot * 64 + quad * 16 + ml;
  const bool hi = r & 1;
  float s0 = 0, s1 = 0, s2 = 0, s3 = 0;
  for (int z = 0; z < 8; ++z) {
    uint4 v = *(const uint4*)(src + (long)z * 1048576);
    if (hi) { s0 += bf_hi(v.x); s1 += bf_hi(v.y); s2 += bf_hi(v.z); s3 += bf_hi(v.w); }
    else    { s0 += bf_lo(v.x); s1 += bf_lo(v.y); s2 += bf_lo(v.z); s3 += bf_lo(v.w); }
  }
  const float sc = 1.f / 2097152.f;                // undo adj x8192 * h1 x256
  *(uint2*)(P_t + o) = make_uint2(pk2(s0 * sc, s1 * sc), pk2(s2 * sc, s3 * sc));
}

// ---------- tail: selu(mean) | fc1 | attention | log_softmax (exact fp32) ----------
__global__ void tail_kernel(const float* __restrict__ gacc, const float* __restrict__ sub_fea,
                            const float* __restrict__ fc1_W, const float* __restrict__ fc1_b,
                            const float* __restrict__ att_W, const float* __restrict__ att_a,
                            const float* __restrict__ att_b, float* __restrict__ out) {
  __shared__ float z[768];
  __shared__ float sc[8];
  __shared__ float alpha[8];
  __shared__ float outsh[10];
  const int t = threadIdx.x;  // 256 threads

  for (int j = t; j < 512; j += 256) {
    float x = gacc[j] * (1.0f / 8192.0f);
    const float scale = 1.0507009873554805f, al = 1.6732632423543772f;
    z[j] = x > 0.f ? scale * x : scale * al * (expf(x) - 1.0f);
  }
  {
    float a = fc1_b[t];
    for (int i = 0; i < 128; ++i) a += sub_fea[i] * fc1_W[i * 256 + t];
    z[512 + t] = a;
  }
  if (t < 10) outsh[t] = 0.f;
  __syncthreads();

  {
    int h = t >> 5, ln = t & 31;
    float p = 0.f;
    for (int i = ln; i < 768; i += 32) p += z[i] * att_a[h * 768 + i];
    for (int m = 16; m; m >>= 1) p += __shfl_down(p, m, 32);
    if (ln == 0) sc[h] = p;
  }
  __syncthreads();
  if (t == 0) {
    float mx = sc[0];
    for (int h = 1; h < 8; ++h) mx = fmaxf(mx, sc[h]);
    float s = 0.f, e[8];
    for (int h = 0; h < 8; ++h) { e[h] = expf(sc[h] - mx); s += e[h]; }
    for (int h = 0; h < 8; ++h) alpha[h] = e[h] / s;
  }
  __syncthreads();

  float p[10];
#pragma unroll
  for (int o = 0; o < 10; ++o) p[o] = 0.f;
  for (int i = t; i < 768; i += 256) {
    float zi = z[i];
    for (int h = 0; h < 8; ++h) {
      float za = zi * alpha[h];
      const float* wp = att_W + (h * 768 + i) * 10;
#pragma unroll
      for (int o = 0; o < 10; ++o) p[o] += za * wp[o];
    }
  }
#pragma unroll
  for (int o = 0; o < 10; ++o) atomicAdd(&outsh[o], p[o]);
  __syncthreads();
  if (t == 0) {
    float v[10], mx = -1e30f;
    for (int o = 0; o < 10; ++o) { v[o] = outsh[o] + att_b[o]; mx = fmaxf(mx, v[o]); }
    float s = 0.f;
    for (int o = 0; o < 10; ++o) s += expf(v[o] - mx);
    float lse = logf(s) + mx;
    for (int o = 0; o < 10; ++o) out[o] = v[o] - lse;
  }
}

// ---------- launch ----------
extern "C" void kernel_launch(void* const* d_in, const int* in_sizes, int n_in,
                              void* d_out, int out_size, void* d_ws, size_t ws_size,
                              hipStream_t stream) {
  const float* x       = (const float*)d_in[0];   // [8192,512]
  const float* adj     = (const float*)d_in[1];   // [8192,8192]
  const float* sub_fea = (const float*)d_in[2];   // [1,128]
  const float* gc1_W   = (const float*)d_in[3];   // [512,256]
  const float* gc1_b   = (const float*)d_in[4];   // [256]
  const float* gc2_W   = (const float*)d_in[5];   // [256,512]
  const float* gc2_b   = (const float*)d_in[6];   // [512]
  const float* fc1_W   = (const float*)d_in[7];   // [128,256]
  const float* fc1_b   = (const float*)d_in[8];   // [256]
  const float* att_W   = (const float*)d_in[9];   // [8,768,10]
  const float* att_a   = (const float*)d_in[10];  // [8,768]
  const float* att_b   = (const float*)d_in[11];  // [10]
  float* out = (float*)d_out;

  const size_t MB = 1u << 20;
  char* ws = (char*)d_ws;
  size_t off = 0;
  u8*       adjT8 = (u8*)      (ws + off); off += 64 * MB;  // fp8 tiled adj (x8192)
  ushort_t* xT    = (ushort_t*)(ws + off); off += 8 * MB;   // bf16 tiled x
  u8*       t1T8  = (u8*)      (ws + off); off += 2 * MB;   // fp8 [256,8192] RB=256
  u8*       h1T8  = (u8*)      (ws + off); off += 2 * MB;   // fp8 [256,8192] RB=256 (x256)
  ushort_t* P_t   = (ushort_t*)(ws + off); off += 4 * MB;   // bf16 [8192,256] RB=128
  u32*      part  = (u32*)     (ws + off); off += 32 * MB;  // [8][64][16384] bf16-pair partials
  ushort_t* W1T   = (ushort_t*)(ws + off); off += 262144;
  ushort_t* W2T   = (ushort_t*)(ws + off); off += 262144;
  float*    gacc  = (float*)   (ws + off);

  hipMemsetAsync(gacc, 0, 512 * sizeof(float), stream);
  prep_t<<<512, 256, 0, stream>>>(gc1_W, gc2_W, W1T, W2T);
  tile_cvt<<<dim3(2, 64), 256, 0, stream>>>(x, xT, 512);

  // L1a: t1 = W1T * x^T -> fp8 tiled (scale 1; t1 ~ N(0,1) fits e4m3)
  gemm_t<128, 128, 5><<<dim3(64, 2, 1), 256, 0, stream>>>(
      W1T, xT, nullptr, t1T8, nullptr, 512, 8192);

  // adj -> fp8 tiled, scaled x8192 into e4m3 normal range
  tile_cvt8<<<dim3(32, 64), 256, 0, stream>>>(adj, adjT8);

  // L1b: s1S[256,8192] = t1 * (adj*8192)^T, fp8 MFMA, split-K=8
  gemm8_t<256, 128><<<dim3(64, 1, 8), 256, 0, stream>>>(t1T8, adjT8, part, 8192);
  reduce_L1b<<<2048, 256, 0, stream>>>(part, h1T8, gc1_b);

  // L2a: PS[8192,256] = (adj*8192) * (h1*256), fp8 MFMA, split-K=8
  gemm8_t<128, 256><<<dim3(1, 64, 8), 256, 0, stream>>>(adjT8, h1T8, part, 8192);
  reduce_L2a<<<2048, 256, 0, stream>>>(part, P_t);

  // L2b: t2T = W2T * P^T ; relu(+gc2_b) row-sum -> gacc (bf16 path)
  gemm_t<128, 128, 2><<<dim3(64, 4, 1), 256, 0, stream>>>(
      W2T, P_t, gc2_b, nullptr, gacc, 256, 8192);

  tail_kernel<<<1, 256, 0, stream>>>(gacc, sub_fea, fc1_W, fc1_b, att_W, att_a, att_b, out);
}